// Round 1
// baseline (342.657 us; speedup 1.0000x reference)
//
#include <hip/hip_runtime.h>
#include <math.h>

#define BB 8
#define SS 512
#define DDIM 1024

// ---------------- zero workspace accumulators ----------------
__global__ void zero_k(float* __restrict__ p) {
    p[(size_t)blockIdx.x * 256 + threadIdx.x] = 0.f;
}

// ---------------- x mean over S (split-S, atomic accumulate) ----------------
// grid: 256 blocks = B(8) x 32 s-chunks of 16; block: 256 threads (one float4 of D each)
__global__ void xsum_k(const float* __restrict__ x, float* __restrict__ xsum) {
    int b  = blockIdx.x >> 5;
    int sc = blockIdx.x & 31;
    int t  = threadIdx.x;
    const float4* x4 = (const float4*)x;
    size_t base = ((size_t)b * SS + (size_t)sc * 16) * (DDIM / 4);
    float4 a = make_float4(0.f, 0.f, 0.f, 0.f);
#pragma unroll
    for (int ss = 0; ss < 16; ++ss) {
        float4 v = x4[base + (size_t)ss * (DDIM / 4) + t];
        a.x += v.x; a.y += v.y; a.z += v.z; a.w += v.w;
    }
    float* dst = xsum + (size_t)b * DDIM + (size_t)t * 4;
    unsafeAtomicAdd(dst + 0, a.x);
    unsafeAtomicAdd(dst + 1, a.y);
    unsafeAtomicAdd(dst + 2, a.z);
    unsafeAtomicAdd(dst + 3, a.w);
}

// ---------------- generic batch-8 vec-mat with split-K atomics ----------------
// out[b,j] (+= bias[j] once) = sum_k act(in[b,k]*premul) * W[k,j]
// ACT: 0=identity 1=tanh 2=silu 3=*quantum-scale(vqc)
// grid: (Dout/256, K/KC); block 256
template <int ACT, int KC>
__global__ void mv_k(const float* __restrict__ in_acc, const float* __restrict__ W,
                     const float* __restrict__ bias, float* __restrict__ out_acc,
                     const float* __restrict__ vqc, float premul, int K, int Dout) {
    __shared__ float sin_[KC * 8];
    int tid = threadIdx.x;
    int j   = blockIdx.x * 256 + tid;
    int k0  = blockIdx.y * KC;
    if (tid < 8 * KC) {
        int b = tid / KC, kk = tid % KC;
        float v = in_acc[(size_t)b * K + k0 + kk] * premul;
        if (ACT == 1) {
            v = tanhf(v);
        } else if (ACT == 2) {
            v = v / (1.f + expf(-v));
        } else if (ACT == 3) {
            float th = vqc[(size_t)(k0 + kk) * 4 + 0] * 0.5f;
            float ph = vqc[(size_t)(k0 + kk) * 4 + 1];
            v *= (cosf(th) + sinf(th) * cosf(ph));
        }
        sin_[kk * 8 + b] = v;
    }
    __syncthreads();
    float acc[8];
#pragma unroll
    for (int b = 0; b < 8; ++b) acc[b] = 0.f;
    const float* wp = W + (size_t)k0 * Dout + j;
#pragma unroll
    for (int kk = 0; kk < KC; ++kk) {
        float w   = wp[(size_t)kk * Dout];
        float4 lo = *(const float4*)&sin_[kk * 8 + 0];
        float4 hi = *(const float4*)&sin_[kk * 8 + 4];
        acc[0] += lo.x * w; acc[1] += lo.y * w; acc[2] += lo.z * w; acc[3] += lo.w * w;
        acc[4] += hi.x * w; acc[5] += hi.y * w; acc[6] += hi.z * w; acc[7] += hi.w * w;
    }
    float bj = (bias != nullptr && blockIdx.y == 0) ? bias[j] : 0.f;
#pragma unroll
    for (int b = 0; b < 8; ++b)
        unsafeAtomicAdd(&out_acc[(size_t)b * Dout + j], acc[b] + bj);
}

// ---------------- memory retrieval stage (one block per batch row) ----------------
__global__ void mem_k(const float* __restrict__ macc, const float* __restrict__ mew2,
                      const float* __restrict__ meb2, const float* __restrict__ mem_states,
                      const float* __restrict__ ret_w1, const float* __restrict__ ret_b1,
                      const float* __restrict__ ret_w2, const float* __restrict__ ret_b2,
                      const float* __restrict__ yv, float* __restrict__ comb) {
    __shared__ float sh_t[DDIM];
    __shared__ float sh_p[256];
    __shared__ float sh_mq[16];
    __shared__ float sh_sc[512];
    __shared__ float sh_rv[256];
    __shared__ int   sh_ri[256];
    __shared__ float sh_f1[24];
    __shared__ float sh_fb[8];
    __shared__ int   sh_top[3];
    int b = blockIdx.x, t = threadIdx.x;
    for (int i = t; i < DDIM; i += 256) sh_t[i] = tanhf(macc[(size_t)b * DDIM + i]);
    __syncthreads();
    {   // mq = tanh(macc) @ mew2 + meb2   (16 outputs, 16-way K split)
        int j = t & 15, g = t >> 4;
        float s = 0.f;
        int kbase = g * 64;
        for (int k = 0; k < 64; ++k) s += sh_t[kbase + k] * mew2[(size_t)(kbase + k) * 16 + j];
        sh_p[t] = s;
    }
    __syncthreads();
    if (t < 16) {
        float v = 0.f;
        for (int g = 0; g < 16; ++g) v += sh_p[g * 16 + t];
        sh_mq[t] = v + meb2[t];
    }
    __syncthreads();
    // scores = (mq . mem_states[m])^2  (softmax is monotone -> skip)
    for (int m = t; m < 512; m += 256) {
        float d = 0.f;
#pragma unroll
        for (int i = 0; i < 16; ++i) d += sh_mq[i] * mem_states[m * 16 + i];
        sh_sc[m] = d * d;
    }
    __syncthreads();
    // top-3 (argsort tail: ties prefer larger index)
    for (int r = 0; r < 3; ++r) {
        float bv = -1.f; int bi = -1;
        for (int m = t; m < 512; m += 256) {
            float v = sh_sc[m];
            if (v > bv || (v == bv && m > bi)) { bv = v; bi = m; }
        }
        sh_rv[t] = bv; sh_ri[t] = bi;
        __syncthreads();
        for (int st = 128; st > 0; st >>= 1) {
            if (t < st) {
                float v2 = sh_rv[t + st]; int i2 = sh_ri[t + st];
                if (v2 > sh_rv[t] || (v2 == sh_rv[t] && i2 > sh_ri[t])) { sh_rv[t] = v2; sh_ri[t] = i2; }
            }
            __syncthreads();
        }
        if (t == 0) { sh_top[r] = sh_ri[0]; sh_sc[sh_ri[0]] = -1.f; }
        __syncthreads();
    }
    // f1[k] = tanh(retr[k,:8] @ ret_w1 + ret_b1)
    if (t < 24) {
        int k = t >> 3, i = t & 7;
        int m = sh_top[k];
        float a = ret_b1[i];
#pragma unroll
        for (int ii = 0; ii < 8; ++ii) a += mem_states[m * 16 + ii] * ret_w1[ii * 8 + i];
        sh_f1[k * 8 + i] = tanhf(a);
    }
    __syncthreads();
    if (t < 8) sh_fb[t] = (sh_f1[t] + sh_f1[8 + t] + sh_f1[16 + t]) * (1.f / 3.f);
    __syncthreads();
    // comb = [y2, mem_ctx]
    for (int jj = t; jj < DDIM; jj += 256) {
        float v = ret_b2[jj];
#pragma unroll
        for (int i = 0; i < 8; ++i) v += sh_fb[i] * ret_w2[(size_t)i * DDIM + jj];
        comb[(size_t)b * 2048 + 1024 + jj] = v;
        comb[(size_t)b * 2048 + jj]        = yv[(size_t)b * DDIM + jj];
    }
}

// ---------------- layernorm per batch row ----------------
__global__ void ln_k(const float* __restrict__ hb, const float* __restrict__ sc,
                     const float* __restrict__ of, float* __restrict__ row) {
    __shared__ float rs[256], rq[256];
    int b = blockIdx.x, t = threadIdx.x;
    float s = 0.f, q = 0.f;
    for (int i = t; i < DDIM; i += 256) {
        float v = hb[(size_t)b * DDIM + i];
        s += v; q += v * v;
    }
    rs[t] = s; rq[t] = q;
    __syncthreads();
    for (int st = 128; st > 0; st >>= 1) {
        if (t < st) { rs[t] += rs[t + st]; rq[t] += rq[t + st]; }
        __syncthreads();
    }
    float mu  = rs[0] * (1.f / DDIM);
    float var = rq[0] * (1.f / DDIM) - mu * mu;
    var = var < 0.f ? 0.f : var;
    float inv = 1.f / sqrtf(var + 1e-5f);
    for (int i = t; i < DDIM; i += 256) {
        float v = hb[(size_t)b * DDIM + i];
        row[(size_t)b * DDIM + i] = (v - mu) * inv * sc[i] + of[i];
    }
}

// ---------------- broadcast 8 rows -> (B,S,D) ----------------
__global__ void bcast_k(const float* __restrict__ row, float4* __restrict__ out) {
    unsigned f  = blockIdx.x * 256u + threadIdx.x;  // < B*S*D/4 = 1048576
    unsigned d4 = f & 255u;                          // D/4 = 256
    unsigned b  = f >> 17;                           // S*D/4 = 131072
    out[f] = ((const float4*)row)[(b << 8) + d4];
}

extern "C" void kernel_launch(void* const* d_in, const int* in_sizes, int n_in,
                              void* d_out, int out_size, void* d_ws, size_t ws_size,
                              hipStream_t stream) {
    const float* x      = (const float*)d_in[0];
    const float* w_v    = (const float*)d_in[5];
    const float* b_v    = (const float*)d_in[6];
    const float* w_o    = (const float*)d_in[7];
    const float* b_o    = (const float*)d_in[8];
    const float* aw1    = (const float*)d_in[15];
    const float* ab1    = (const float*)d_in[16];
    const float* aw2    = (const float*)d_in[17];
    const float* ab2    = (const float*)d_in[18];
    const float* vqc    = (const float*)d_in[19];
    const float* pw1    = (const float*)d_in[20];
    const float* pb1    = (const float*)d_in[21];
    const float* pw2    = (const float*)d_in[22];
    const float* pb2    = (const float*)d_in[23];
    const float* mew1   = (const float*)d_in[24];
    const float* meb1   = (const float*)d_in[25];
    const float* mew2   = (const float*)d_in[26];
    const float* meb2   = (const float*)d_in[27];
    const float* mst    = (const float*)d_in[28];
    const float* rw1    = (const float*)d_in[29];
    const float* rb1    = (const float*)d_in[30];
    const float* rw2    = (const float*)d_in[31];
    const float* rb2    = (const float*)d_in[32];
    const float* brw1   = (const float*)d_in[33];
    const float* brb1   = (const float*)d_in[34];
    const float* brw2   = (const float*)d_in[35];
    const float* brb2   = (const float*)d_in[36];
    const float* lnsc   = (const float*)d_in[37];
    const float* lnof   = (const float*)d_in[38];

    float* ws    = (float*)d_ws;
    float* xsum  = ws;              // 8192  (accumulated)
    float* vfull = ws + 8192;       // 8192  (accumulated)
    float* yacc  = ws + 16384;      // 8192  (accumulated, y0 then y+=h1)
    float* t0    = ws + 24576;      // 8192
    float* a0    = ws + 32768;      // 8192
    float* s0a   = ws + 40960;      // 8192
    float* t1    = ws + 49152;      // 8192
    float* a1    = ws + 57344;      // 8192
    float* s1a   = ws + 65536;      // 8192
    float* macc  = ws + 73728;      // 8192
    float* hba   = ws + 81920;      // 16384 (B x 2048)
    float* hbacc = ws + 98304;      // 8192
    // --- end of zeroed accumulator region: 106496 floats ---
    float* comb  = ws + 106496;     // 16384 (written fully, no zero needed)
    float* row   = ws + 122880;     // 8192

    const int DDm = DDIM * DDIM;

    // zero accumulators (106496 = 416*256)
    zero_k<<<416, 256, 0, stream>>>(ws);

    // xmean (as sum; /512 folded into premul of next stage)
    xsum_k<<<256, 256, 0, stream>>>(x, xsum);

    dim3 g1(4, 64);   // Dout=1024, K=1024, KC=16
    // Vmean = xmean @ w_v + b_v
    mv_k<0, 16><<<g1, 256, 0, stream>>>(xsum, w_v, b_v, vfull, nullptr, 1.f / 512.f, 1024, 1024);
    // y0 = Vmean @ w_o + b_o
    mv_k<0, 16><<<g1, 256, 0, stream>>>(vfull, w_o, b_o, yacc, nullptr, 1.f, 1024, 1024);
    // quantum layer 0
    mv_k<0, 16><<<g1, 256, 0, stream>>>(yacc, aw1, ab1, t0, nullptr, 1.f, 1024, 1024);
    mv_k<1, 16><<<g1, 256, 0, stream>>>(t0, aw2, ab2, a0, nullptr, 1.f, 1024, 1024);
    mv_k<3, 16><<<g1, 256, 0, stream>>>(a0, pw1, pb1, s0a, vqc, 1.f, 1024, 1024);
    mv_k<2, 16><<<g1, 256, 0, stream>>>(s0a, pw2, pb2, yacc, nullptr, 1.f, 1024, 1024);
    // quantum layer 1
    mv_k<0, 16><<<g1, 256, 0, stream>>>(yacc, aw1 + DDm, ab1 + 1024, t1, nullptr, 1.f, 1024, 1024);
    mv_k<1, 16><<<g1, 256, 0, stream>>>(t1, aw2 + DDm, ab2 + 1024, a1, nullptr, 1.f, 1024, 1024);
    mv_k<3, 16><<<g1, 256, 0, stream>>>(a1, pw1 + DDm, pb1 + 1024, s1a, vqc + 4096, 1.f, 1024, 1024);
    mv_k<2, 16><<<g1, 256, 0, stream>>>(s1a, pw2 + DDm, pb2 + 1024, yacc, nullptr, 1.f, 1024, 1024);
    // memory encoder first matmul
    mv_k<0, 16><<<g1, 256, 0, stream>>>(yacc, mew1, meb1, macc, nullptr, 1.f, 1024, 1024);
    // mq, top-3 retrieval, comb = [y2, mem_ctx]
    mem_k<<<8, 256, 0, stream>>>(macc, mew2, meb2, mst, rw1, rb1, rw2, rb2, yacc, comb);
    // bridge MLP
    mv_k<0, 32><<<dim3(8, 64), 256, 0, stream>>>(comb, brw1, brb1, hba, nullptr, 1.f, 2048, 2048);
    mv_k<2, 32><<<dim3(4, 64), 256, 0, stream>>>(hba, brw2, brb2, hbacc, nullptr, 1.f, 2048, 1024);
    // layernorm -> 8 rows
    ln_k<<<8, 256, 0, stream>>>(hbacc, lnsc, lnof, row);
    // broadcast to (B,S,D)
    bcast_k<<<4096, 256, 0, stream>>>(row, (float4*)d_out);
}

// Round 2
// 263.070 us; speedup vs baseline: 1.3025x; 1.3025x over previous
//
#include <hip/hip_runtime.h>
#include <math.h>

#define BB 8
#define SS 512
#define DDIM 1024

// ---------------- x sum over S, non-atomic: 32 private partial slices ----------------
// grid: 256 blocks = B(8) x 32 s-chunks of 16 rows; block 256 (one float4 of D each)
// xpart layout: [32][8][1024]
__global__ __launch_bounds__(256) void xsum_k(const float* __restrict__ x,
                                              float* __restrict__ xpart) {
    int b  = blockIdx.x >> 5;
    int sc = blockIdx.x & 31;
    int t  = threadIdx.x;
    const float4* x4 = (const float4*)x;
    size_t base = ((size_t)b * SS + (size_t)sc * 16) * (DDIM / 4);
    float4 a = make_float4(0.f, 0.f, 0.f, 0.f);
#pragma unroll
    for (int ss = 0; ss < 16; ++ss) {
        float4 v = x4[base + (size_t)ss * (DDIM / 4) + t];
        a.x += v.x; a.y += v.y; a.z += v.z; a.w += v.w;
    }
    ((float4*)xpart)[((size_t)sc * 8 + b) * (DDIM / 4) + t] = a;
}

// ---------------- batch-8 vec-mat, atomic-free split-K with private partial slices ----
// in_parts: [NP][8][K] (summed at staging), out_part: [8][8][Dout] (slice blockIdx.y)
// staged value = ACT( premul * sum_p in_parts[p][b][k] ); bias added at ky==0.
// ACT: 0=identity 1=tanh 2=silu 3=*quantum-scale(vqc)
// grid: (Dout/32, 8); block 256. KR = K/8 (128 or 256).
template <int ACT, int NP, int KR>
__global__ __launch_bounds__(256) void mv2_k(const float* __restrict__ in_parts,
                                             const float* __restrict__ W,
                                             const float* __restrict__ bias,
                                             float* __restrict__ out_part,
                                             const float* __restrict__ vqc,
                                             float premul, int K, int Dout) {
    constexpr int NI = KR / 128;             // float4 staging positions per thread
    __shared__ float sin_[8 * KR];           // [b][KR]
    __shared__ float red[256 * 33];          // [out 256][kg 32 +pad]
    int t  = threadIdx.x;
    int j0 = blockIdx.x * 32;
    int k0 = blockIdx.y * KR;

    // ---- staging: sum NP partials, premul, activation, into LDS [b][k] ----
#pragma unroll
    for (int i = 0; i < NI; ++i) {
        int f  = i * 256 + t;                // < 8*KR/4
        int b  = f / (KR / 4);
        int kq = f % (KR / 4);
        const float* src = in_parts + (size_t)b * K + k0 + kq * 4;
        float4 v = make_float4(0.f, 0.f, 0.f, 0.f);
#pragma unroll
        for (int p = 0; p < NP; ++p) {
            float4 u = *(const float4*)(src + (size_t)p * 8 * K);
            v.x += u.x; v.y += u.y; v.z += u.z; v.w += u.w;
        }
        float vv[4] = {v.x * premul, v.y * premul, v.z * premul, v.w * premul};
#pragma unroll
        for (int c = 0; c < 4; ++c) {
            float s = vv[c];
            if (ACT == 1) {
                s = tanhf(s);
            } else if (ACT == 2) {
                s = s / (1.f + expf(-s));
            } else if (ACT == 3) {
                int kk = k0 + kq * 4 + c;
                float th = vqc[(size_t)kk * 4 + 0] * 0.5f;
                float ph = vqc[(size_t)kk * 4 + 1];
                s *= (cosf(th) + sinf(th) * cosf(ph));
            }
            vv[c] = s;
        }
        *(float4*)&sin_[b * KR + kq * 4] = make_float4(vv[0], vv[1], vv[2], vv[3]);
    }
    __syncthreads();

    // ---- compute: thread (kg, jq): 4 j-columns x 8 batches over NI*4 k's ----
    int jq = t & 7, kg = t >> 3;
    float acc[8][4];
#pragma unroll
    for (int b = 0; b < 8; ++b)
#pragma unroll
        for (int c = 0; c < 4; ++c) acc[b][c] = 0.f;
#pragma unroll
    for (int i = 0; i < NI; ++i) {
#pragma unroll
        for (int c = 0; c < 4; ++c) {
            int kl = kg * (NI * 4) + i * 4 + c;
            float4 w4 = *(const float4*)(W + (size_t)(k0 + kl) * Dout + j0 + jq * 4);
#pragma unroll
            for (int b = 0; b < 8; ++b) {
                float s = sin_[b * KR + kl];
                acc[b][0] += s * w4.x; acc[b][1] += s * w4.y;
                acc[b][2] += s * w4.z; acc[b][3] += s * w4.w;
            }
        }
    }

    // ---- reduce 32 kg-groups via LDS ----
#pragma unroll
    for (int b = 0; b < 8; ++b)
#pragma unroll
        for (int c = 0; c < 4; ++c)
            red[(b * 32 + jq * 4 + c) * 33 + kg] = acc[b][c];
    __syncthreads();
    // thread t handles output o = t = b*32 + jc
    float s = 0.f;
#pragma unroll
    for (int g = 0; g < 32; ++g) s += red[t * 33 + g];
    int b = t >> 5, jc = t & 31;
    int j = j0 + jc;
    if (bias != nullptr && blockIdx.y == 0) s += bias[j];
    out_part[(size_t)blockIdx.y * 8 * Dout + (size_t)b * Dout + j] = s;
}

// ---------------- memory retrieval stage (one block per batch row) ----------------
// maccp: [8][8][1024] partials; yparts: [24][8][1024] partials (y = sum of 24)
__global__ __launch_bounds__(256) void mem_k(const float* __restrict__ maccp,
                      const float* __restrict__ mew2,
                      const float* __restrict__ meb2, const float* __restrict__ mem_states,
                      const float* __restrict__ ret_w1, const float* __restrict__ ret_b1,
                      const float* __restrict__ ret_w2, const float* __restrict__ ret_b2,
                      const float* __restrict__ yparts, float* __restrict__ comb) {
    __shared__ float sh_t[DDIM];
    __shared__ float sh_p[256];
    __shared__ float sh_mq[16];
    __shared__ float sh_sc[512];
    __shared__ float sh_rv[256];
    __shared__ int   sh_ri[256];
    __shared__ float sh_f1[24];
    __shared__ float sh_fb[8];
    __shared__ int   sh_top[3];
    int b = blockIdx.x, t = threadIdx.x;
    for (int i = t; i < DDIM; i += 256) {
        float v = 0.f;
#pragma unroll
        for (int p = 0; p < 8; ++p) v += maccp[(size_t)p * 8 * DDIM + (size_t)b * DDIM + i];
        sh_t[i] = tanhf(v);
    }
    __syncthreads();
    {   // mq = tanh(macc) @ mew2 + meb2   (16 outputs, 16-way K split)
        int j = t & 15, g = t >> 4;
        float s = 0.f;
        int kbase = g * 64;
        for (int k = 0; k < 64; ++k) s += sh_t[kbase + k] * mew2[(size_t)(kbase + k) * 16 + j];
        sh_p[t] = s;
    }
    __syncthreads();
    if (t < 16) {
        float v = 0.f;
        for (int g = 0; g < 16; ++g) v += sh_p[g * 16 + t];
        sh_mq[t] = v + meb2[t];
    }
    __syncthreads();
    // scores = (mq . mem_states[m])^2  (softmax monotone -> skip)
    for (int m = t; m < 512; m += 256) {
        float d = 0.f;
#pragma unroll
        for (int i = 0; i < 16; ++i) d += sh_mq[i] * mem_states[m * 16 + i];
        sh_sc[m] = d * d;
    }
    __syncthreads();
    // top-3 (argsort tail: ties prefer larger index)
    for (int r = 0; r < 3; ++r) {
        float bv = -1.f; int bi = -1;
        for (int m = t; m < 512; m += 256) {
            float v = sh_sc[m];
            if (v > bv || (v == bv && m > bi)) { bv = v; bi = m; }
        }
        sh_rv[t] = bv; sh_ri[t] = bi;
        __syncthreads();
        for (int st = 128; st > 0; st >>= 1) {
            if (t < st) {
                float v2 = sh_rv[t + st]; int i2 = sh_ri[t + st];
                if (v2 > sh_rv[t] || (v2 == sh_rv[t] && i2 > sh_ri[t])) { sh_rv[t] = v2; sh_ri[t] = i2; }
            }
            __syncthreads();
        }
        if (t == 0) { sh_top[r] = sh_ri[0]; sh_sc[sh_ri[0]] = -1.f; }
        __syncthreads();
    }
    if (t < 24) {
        int k = t >> 3, i = t & 7;
        int m = sh_top[k];
        float a = ret_b1[i];
#pragma unroll
        for (int ii = 0; ii < 8; ++ii) a += mem_states[m * 16 + ii] * ret_w1[ii * 8 + i];
        sh_f1[k * 8 + i] = tanhf(a);
    }
    __syncthreads();
    if (t < 8) sh_fb[t] = (sh_f1[t] + sh_f1[8 + t] + sh_f1[16 + t]) * (1.f / 3.f);
    __syncthreads();
    // comb = [y, mem_ctx]
    for (int jj = t; jj < DDIM; jj += 256) {
        float v = ret_b2[jj];
#pragma unroll
        for (int i = 0; i < 8; ++i) v += sh_fb[i] * ret_w2[(size_t)i * DDIM + jj];
        comb[(size_t)b * 2048 + 1024 + jj] = v;
        float y = 0.f;
#pragma unroll
        for (int p = 0; p < 24; ++p) y += yparts[(size_t)p * 8 * DDIM + (size_t)b * DDIM + jj];
        comb[(size_t)b * 2048 + jj] = y;
    }
}

// ---------------- layernorm per batch row (input: 8 partial slices) ----------------
__global__ __launch_bounds__(256) void ln_k(const float* __restrict__ hbp,
                     const float* __restrict__ sc,
                     const float* __restrict__ of, float* __restrict__ row) {
    __shared__ float sh_v[DDIM];
    __shared__ float rs[256], rq[256];
    int b = blockIdx.x, t = threadIdx.x;
    float s = 0.f, q = 0.f;
    for (int i = t; i < DDIM; i += 256) {
        float v = 0.f;
#pragma unroll
        for (int p = 0; p < 8; ++p) v += hbp[(size_t)p * 8 * DDIM + (size_t)b * DDIM + i];
        sh_v[i] = v;
        s += v; q += v * v;
    }
    rs[t] = s; rq[t] = q;
    __syncthreads();
    for (int st = 128; st > 0; st >>= 1) {
        if (t < st) { rs[t] += rs[t + st]; rq[t] += rq[t + st]; }
        __syncthreads();
    }
    float mu  = rs[0] * (1.f / DDIM);
    float var = rq[0] * (1.f / DDIM) - mu * mu;
    var = var < 0.f ? 0.f : var;
    float inv = 1.f / sqrtf(var + 1e-5f);
    for (int i = t; i < DDIM; i += 256) {
        float v = sh_v[i];
        row[(size_t)b * DDIM + i] = (v - mu) * inv * sc[i] + of[i];
    }
}

// ---------------- broadcast 8 rows -> (B,S,D) ----------------
__global__ __launch_bounds__(256) void bcast_k(const float* __restrict__ row,
                                               float4* __restrict__ out) {
    unsigned f  = blockIdx.x * 256u + threadIdx.x;  // < B*S*D/4 = 1048576
    unsigned d4 = f & 255u;                          // D/4 = 256
    unsigned b  = f >> 17;                           // S*D/4 = 131072
    out[f] = ((const float4*)row)[(b << 8) + d4];
}

extern "C" void kernel_launch(void* const* d_in, const int* in_sizes, int n_in,
                              void* d_out, int out_size, void* d_ws, size_t ws_size,
                              hipStream_t stream) {
    const float* x      = (const float*)d_in[0];
    const float* w_v    = (const float*)d_in[5];
    const float* b_v    = (const float*)d_in[6];
    const float* w_o    = (const float*)d_in[7];
    const float* b_o    = (const float*)d_in[8];
    const float* aw1    = (const float*)d_in[15];
    const float* ab1    = (const float*)d_in[16];
    const float* aw2    = (const float*)d_in[17];
    const float* ab2    = (const float*)d_in[18];
    const float* vqc    = (const float*)d_in[19];
    const float* pw1    = (const float*)d_in[20];
    const float* pb1    = (const float*)d_in[21];
    const float* pw2    = (const float*)d_in[22];
    const float* pb2    = (const float*)d_in[23];
    const float* mew1   = (const float*)d_in[24];
    const float* meb1   = (const float*)d_in[25];
    const float* mew2   = (const float*)d_in[26];
    const float* meb2   = (const float*)d_in[27];
    const float* mst    = (const float*)d_in[28];
    const float* rw1    = (const float*)d_in[29];
    const float* rb1    = (const float*)d_in[30];
    const float* rw2    = (const float*)d_in[31];
    const float* rb2    = (const float*)d_in[32];
    const float* brw1   = (const float*)d_in[33];
    const float* brb1   = (const float*)d_in[34];
    const float* brw2   = (const float*)d_in[35];
    const float* brb2   = (const float*)d_in[36];
    const float* lnsc   = (const float*)d_in[37];
    const float* lnof   = (const float*)d_in[38];

    float* ws     = (float*)d_ws;
    float* xpart  = ws;               // [32][8][1024]  262144
    float* vfullp = ws + 262144;      // [8][8][1024]    65536
    float* yparts = ws + 327680;      // [24][8][1024]  196608 (y0|h0|h1)
    float* t0p    = ws + 524288;      // [8][8][1024]    65536 (reused l0/l1)
    float* a0p    = ws + 589824;      // [8][8][1024]    65536
    float* s0p    = ws + 655360;      // [8][8][1024]    65536
    float* maccp  = ws + 720896;      // [8][8][1024]    65536
    float* comb   = ws + 786432;      // [8][2048]       16384
    float* hbap   = ws + 802816;      // [8][8][2048]   131072
    float* hbccp  = ws + 933888;      // [8][8][1024]    65536
    float* row    = ws + 999424;      // [8][1024]        8192

    float* y0p = yparts;
    float* h0p = yparts + 65536;
    float* h1p = yparts + 131072;
    const int DDm = DDIM * DDIM;

    // x row-sums, 32 private slices
    xsum_k<<<256, 256, 0, stream>>>(x, xpart);

    dim3 g1(32, 8);   // Dout=1024, K=1024, KR=128
    // Vmean = (xsum/512) @ w_v + b_v
    mv2_k<0, 32, 128><<<g1, 256, 0, stream>>>(xpart, w_v, b_v, vfullp, nullptr, 1.f / 512.f, 1024, 1024);
    // y0 = Vmean @ w_o + b_o
    mv2_k<0, 8, 128><<<g1, 256, 0, stream>>>(vfullp, w_o, b_o, y0p, nullptr, 1.f, 1024, 1024);
    // quantum layer 0   (y = y0)
    mv2_k<0, 8, 128><<<g1, 256, 0, stream>>>(y0p, aw1, ab1, t0p, nullptr, 1.f, 1024, 1024);
    mv2_k<1, 8, 128><<<g1, 256, 0, stream>>>(t0p, aw2, ab2, a0p, nullptr, 1.f, 1024, 1024);
    mv2_k<3, 8, 128><<<g1, 256, 0, stream>>>(a0p, pw1, pb1, s0p, vqc, 1.f, 1024, 1024);
    mv2_k<2, 8, 128><<<g1, 256, 0, stream>>>(s0p, pw2, pb2, h0p, nullptr, 1.f, 1024, 1024);
    // quantum layer 1   (y = y0 + h0 -> NP=16 from yparts base)
    mv2_k<0, 16, 128><<<g1, 256, 0, stream>>>(yparts, aw1 + DDm, ab1 + 1024, t0p, nullptr, 1.f, 1024, 1024);
    mv2_k<1, 8, 128><<<g1, 256, 0, stream>>>(t0p, aw2 + DDm, ab2 + 1024, a0p, nullptr, 1.f, 1024, 1024);
    mv2_k<3, 8, 128><<<g1, 256, 0, stream>>>(a0p, pw1 + DDm, pb1 + 1024, s0p, vqc + 4096, 1.f, 1024, 1024);
    mv2_k<2, 8, 128><<<g1, 256, 0, stream>>>(s0p, pw2 + DDm, pb2 + 1024, h1p, nullptr, 1.f, 1024, 1024);
    // memory encoder first matmul (y = y0+h0+h1 -> NP=24)
    mv2_k<0, 24, 128><<<g1, 256, 0, stream>>>(yparts, mew1, meb1, maccp, nullptr, 1.f, 1024, 1024);
    // mq, top-3 retrieval, comb = [y, mem_ctx]
    mem_k<<<8, 256, 0, stream>>>(maccp, mew2, meb2, mst, rw1, rb1, rw2, rb2, yparts, comb);
    // bridge MLP
    mv2_k<0, 1, 256><<<dim3(64, 8), 256, 0, stream>>>(comb, brw1, brb1, hbap, nullptr, 1.f, 2048, 2048);
    mv2_k<2, 8, 256><<<dim3(32, 8), 256, 0, stream>>>(hbap, brw2, brb2, hbccp, nullptr, 1.f, 2048, 1024);
    // layernorm -> 8 rows
    ln_k<<<8, 256, 0, stream>>>(hbccp, lnsc, lnof, row);
    // broadcast to (B,S,D)
    bcast_k<<<4096, 256, 0, stream>>>(row, (float4*)d_out);
}